// Round 4
// baseline (953.974 us; speedup 1.0000x reference)
//
#include <hip/hip_runtime.h>

#define CI   128
#define TT   8192
#define CO   256
#define KW   9
#define NQ   5
#define PADL 4
#define KDIM (CI*KW)       // 1152
#define NSTEP 36           // K-steps (K=32) per q
#define NF (NQ*NSTEP)      // 180
#define BCO  128
#define BT   256
#define XROWS 264          // 256 + 8 halo
#define XPITCH 136         // 272B rows = 17 x 16B granules (odd) -> octet-clean reads
#define WBUF_SHORTS (BCO*32)

typedef __attribute__((ext_vector_type(8))) short short8;
typedef __attribute__((ext_vector_type(4))) float float4v;
typedef __attribute__((address_space(1))) const unsigned int ga_u32;
typedef __attribute__((address_space(3))) unsigned int la_u32;

static __device__ __forceinline__ short f2bf(float f) {
  union { float f; unsigned u; } c; c.f = f;
  unsigned u = c.u;
  return (short)((u + 0x7FFFu + ((u >> 16) & 1u)) >> 16);  // RNE
}

static __device__ __forceinline__ float tanh_fast(float z) {
  float e = __expf(2.f * z);
  return (e - 1.f) / (e + 1.f);
}

static __device__ __forceinline__ void gload_lds16(const short* g, short* l) {
  __builtin_amdgcn_global_load_lds((ga_u32*)g, (la_u32*)l, 16, 0, 0);
}

// ---- kernel 1: conv_weights (CO,CI,KW,NQ) fp32 -> wT[q][co][k*128+ci] bf16 ----
__global__ void selfonn_wtrans(const float* __restrict__ w, short* __restrict__ wT, int n) {
  int o = blockIdx.x * 256 + threadIdx.x;
  if (o >= n) return;
  int ci = o & (CI - 1);
  int k  = (o >> 7) % KW;
  int co = (o / KDIM) & (CO - 1);
  int q  = o / (KDIM * CO);
  wT[o] = f2bf(w[((co * CI + ci) * KW + k) * NQ + q]);
}

// ---- kernel 2: fused implicit-GEMM conv + nonlinearities + weighted sum ----
// 4 waves, 1 wave/SIMD; per-wave 128co x 64t (8x4 fragments); full frag prefetch.
__global__ __launch_bounds__(256, 1) void selfonn_main(
    const float* __restrict__ x, const short* __restrict__ wT,
    const float* __restrict__ probs, float* __restrict__ out) {

  __shared__ __align__(16) short xs[XROWS][XPITCH];         // 71808 B
  __shared__ __align__(16) short ws[3][WBUF_SHORTS];        // 24576 B, slot-swizzled
  __shared__ float opw[BCO][NQ];                            // 2560 B

  const int tid  = threadIdx.x;
  const int lane = tid & 63;
  const int wid  = tid >> 6;   // wave 0..3 -> t-quadrant
  const int wn   = wid;
  const int l15  = lane & 15;
  const int lg   = lane >> 4;  // 0..3
  const int b    = blockIdx.z;
  const int co0  = blockIdx.y * BCO;
  const int t0   = blockIdx.x * BT;

  // operator softmax -> LDS
  if (tid < BCO) {
    float p[NQ];
    float mx = -1e30f;
    #pragma unroll
    for (int j = 0; j < NQ; ++j) { p[j] = probs[(co0 + tid) * NQ + j]; mx = fmaxf(mx, p[j]); }
    float s = 0.f;
    #pragma unroll
    for (int j = 0; j < NQ; ++j) { p[j] = __expf(p[j] - mx); s += p[j]; }
    float inv = 1.0f / s;
    #pragma unroll
    for (int j = 0; j < NQ; ++j) opw[tid][j] = p[j] * inv;
  }

  // ---- staging address precompute (inverse-swizzled global source) ----
  // LDS granule G holds ws row co_l = G>>2, PHYS slot G&3.
  // logical slot = (G - (G>>3)) & 3.
  int soff0, soff1;
  {
    int G0 = tid, G1 = 256 + tid;
    soff0 = (G0 >> 2) * KDIM + (((G0 - (G0 >> 3)) & 3) << 3);
    soff1 = (G1 >> 2) * KDIM + (((G1 - (G1 >> 3)) & 3) << 3);
  }
  const int sdst0 = (wid * 64) * 8;        // shorts; HW adds lane*16B
  const int sdst1 = (256 + wid * 64) * 8;
  const short* wTb = wT + (size_t)co0 * KDIM;

  // issue stage(0) -> ws[0], stage(1) -> ws[1] early (overlap with xs staging)
  gload_lds16(wTb + soff0,      &ws[0][0] + sdst0);
  gload_lds16(wTb + soff1,      &ws[0][0] + sdst1);
  gload_lds16(wTb + soff0 + 32, &ws[1][0] + sdst0);
  gload_lds16(wTb + soff1 + 32, &ws[1][0] + sdst1);

  // stage x tile once (t-transposed, bf16): xs[tl][ci] = x[b][ci][t0-4+tl]
  const float* xb = x + (size_t)b * CI * TT;
  for (int it = 0; it < 33; ++it) {
    int cell = tid + it * 256;          // 0..8447 = 66 t-cells x 128 ci
    int ci = cell & (CI - 1);
    int tc = cell >> 7;                 // 0..65
    int tg = t0 - PADL + tc * 4;
    float4v v = {0.f, 0.f, 0.f, 0.f};
    if (tg >= 0 && tg <= TT - 4)
      v = *(const float4v*)(xb + (size_t)ci * TT + tg);
    int tl = tc * 4;
    xs[tl + 0][ci] = f2bf(v[0]);
    xs[tl + 1][ci] = f2bf(v[1]);
    xs[tl + 2][ci] = f2bf(v[2]);
    xs[tl + 3][ci] = f2bf(v[3]);
  }

  // ---- ds_read offset precompute ----
  int afo[8], bfo[4];
  #pragma unroll
  for (int m = 0; m < 8; ++m)
    afo[m] = (m * 16 + l15) * 32 + (((lg + (l15 >> 1)) & 3) << 3);
  #pragma unroll
  for (int n = 0; n < 4; ++n)
    bfo[n] = (wn * 64 + n * 16 + l15) * XPITCH + (lg << 3);

  float4v oacc[8][4];
  float4v acc[8][4];
  #pragma unroll
  for (int m = 0; m < 8; ++m)
    #pragma unroll
    for (int n = 0; n < 4; ++n) {
      oacc[m][n] = (float4v){0.f, 0.f, 0.f, 0.f};
      acc[m][n]  = (float4v){0.f, 0.f, 0.f, 0.f};
    }

  __syncthreads();   // drains stage(0),(1) for ALL waves + xs/opw writes

  short8 afA[8], afB[8], bvA[4], bvB[4];
  // prologue: read frag(0) (q0, step0: k=0, ci0=0) into A
  #pragma unroll
  for (int m = 0; m < 8; ++m) afA[m] = *(const short8*)(&ws[0][0] + afo[m]);
  #pragma unroll
  for (int n = 0; n < 4; ++n) bvA[n] = *(const short8*)(&xs[0][0] + bfo[n]);

  int q = 0, s = 0;
  int sb = 2, nb = 1;           // stage target buf, next-frag buf
  int s_step = 2, s_qoff = 0;   // stage cursor = fi+2

  #define EPILOGUE()                                                   \
    {                                                                  \
      _Pragma("unroll") for (int m = 0; m < 8; ++m) {                  \
        _Pragma("unroll") for (int jj = 0; jj < 4; ++jj) {             \
          int co_l = m * 16 + lg * 4 + jj;                             \
          float wqv = opw[co_l][q];                                    \
          _Pragma("unroll") for (int n = 0; n < 4; ++n) {              \
            float z = acc[m][n][jj];                                   \
            float f;                                                   \
            if (q == 0)      f = z;                                    \
            else if (q == 1) f = __sinf(z);                            \
            else if (q == 2) f = __cosf(z);                            \
            else if (q == 3) f = tanh_fast(z);                         \
            else             f = __expf(fminf(fmaxf(z, -8.f), 8.f));   \
            oacc[m][n][jj] += wqv * f;                                 \
            acc[m][n][jj] = 0.f;                                       \
          }                                                            \
        }                                                              \
      }                                                                \
    }

  #define BODY(FI, CAF, CBV, NAF, NBV)                                 \
    {                                                                  \
      if ((FI) < NF - 2) {                                             \
        const short* wp = wTb + s_qoff + s_step * 32;                  \
        short* lb = &ws[sb][0];                                        \
        gload_lds16(wp + soff0, lb + sdst0);                           \
        gload_lds16(wp + soff1, lb + sdst1);                           \
        if (++s_step == NSTEP) { s_step = 0; s_qoff += CO * KDIM; }    \
        asm volatile("s_waitcnt vmcnt(2)" ::: "memory");               \
      } else {                                                         \
        asm volatile("s_waitcnt vmcnt(0)" ::: "memory");               \
      }                                                                \
      asm volatile("s_barrier" ::: "memory");                          \
      {                                                                \
        int snx = (s == NSTEP - 1) ? 0 : s + 1;                        \
        int kn  = snx >> 2;                                            \
        int cn  = (snx & 3) << 5;                                      \
        const short* bb = &ws[nb][0];                                  \
        _Pragma("unroll") for (int m = 0; m < 8; ++m)                  \
          NAF[m] = *(const short8*)(bb + afo[m]);                      \
        const short* xp = &xs[0][0] + kn * XPITCH + cn;                \
        _Pragma("unroll") for (int n = 0; n < 4; ++n)                  \
          NBV[n] = *(const short8*)(xp + bfo[n]);                      \
      }                                                                \
      __builtin_amdgcn_s_setprio(1);                                   \
      _Pragma("unroll") for (int m = 0; m < 8; ++m)                    \
        _Pragma("unroll") for (int n = 0; n < 4; ++n)                  \
          acc[m][n] = __builtin_amdgcn_mfma_f32_16x16x32_bf16(         \
              CAF[m], CBV[n], acc[m][n], 0, 0, 0);                     \
      __builtin_amdgcn_s_setprio(0);                                   \
      if (s == NSTEP - 1) EPILOGUE();                                  \
      if (++s == NSTEP) { s = 0; ++q; }                                \
      sb = (sb == 2) ? 0 : sb + 1;                                     \
      nb = (nb == 2) ? 0 : nb + 1;                                     \
    }

  for (int fi2 = 0; fi2 < NF; fi2 += 2) {
    BODY(fi2,     afA, bvA, afB, bvB)
    BODY(fi2 + 1, afB, bvB, afA, bvA)
  }
  #undef BODY
  #undef EPILOGUE

  // store (B, CO, T) fp32
  float* ob = out + (size_t)(b * CO + co0) * TT;
  #pragma unroll
  for (int m = 0; m < 8; ++m) {
    #pragma unroll
    for (int jj = 0; jj < 4; ++jj) {
      int co_l = m * 16 + lg * 4 + jj;
      int tcol = t0 + wn * 64 + l15;
      float* orow = ob + (size_t)co_l * TT + tcol;
      #pragma unroll
      for (int n = 0; n < 4; ++n)
        orow[n * 16] = oacc[m][n][jj];
    }
  }
}

extern "C" void kernel_launch(void* const* d_in, const int* in_sizes, int n_in,
                              void* d_out, int out_size, void* d_ws, size_t ws_size,
                              hipStream_t stream) {
  const float* x     = (const float*)d_in[0];
  const float* w     = (const float*)d_in[1];
  const float* probs = (const float*)d_in[2];
  float* out = (float*)d_out;
  short* wT  = (short*)d_ws;   // NQ*CO*KDIM*2 = 2.95 MB

  int nw = NQ * CO * KDIM;
  selfonn_wtrans<<<dim3((nw + 255) / 256), 256, 0, stream>>>(w, wT, nw);

  dim3 grid(TT / BT, CO / BCO, 16);
  selfonn_main<<<grid, 256, 0, stream>>>(x, wT, probs, out);
}

// Round 5
// 552.284 us; speedup vs baseline: 1.7273x; 1.7273x over previous
//
#include <hip/hip_runtime.h>

#define CI   128
#define TT   8192
#define CO   256
#define KW   9
#define NQ   5
#define PADL 4
#define KDIM (CI*KW)       // 1152
#define NSTEP 36           // K32 steps per q
#define NF (NQ*NSTEP)      // 180
#define BCO  128
#define BT   256
#define XROWS 264          // 256 + 8 halo
#define XPITCH 136         // 272B rows: odd granule count -> uniform bank spread
#define WRING 5
#define WSLOT (BCO*32)     // 4096 shorts = 8KB per ring slot

typedef __attribute__((ext_vector_type(8))) short short8;
typedef __attribute__((ext_vector_type(4))) float float4v;
typedef __attribute__((address_space(1))) const unsigned int ga_u32;
typedef __attribute__((address_space(3))) unsigned int la_u32;

static __device__ __forceinline__ short f2bf(float f) {
  union { float f; unsigned u; } c; c.f = f;
  unsigned u = c.u;
  return (short)((u + 0x7FFFu + ((u >> 16) & 1u)) >> 16);  // RNE
}

static __device__ __forceinline__ float tanh_fast(float z) {
  float e = __expf(2.f * z);
  return (e - 1.f) / (e + 1.f);
}

static __device__ __forceinline__ void gload_lds16(const short* g, short* l) {
  __builtin_amdgcn_global_load_lds((ga_u32*)g, (la_u32*)l, 16, 0, 0);
}

// ---- kernel 1: conv_weights (CO,CI,KW,NQ) fp32 -> wT[q][co][k*128+ci] bf16 ----
__global__ void selfonn_wtrans(const float* __restrict__ w, short* __restrict__ wT, int n) {
  int o = blockIdx.x * 256 + threadIdx.x;
  if (o >= n) return;
  int ci = o & (CI - 1);
  int k  = (o >> 7) % KW;
  int co = (o / KDIM) & (CO - 1);
  int q  = o / (KDIM * CO);
  wT[o] = f2bf(w[((co * CI + ci) * KW + k) * NQ + q]);
}

// ---- kernel 2: fused implicit-GEMM conv + nonlinearities + weighted sum ----
// 8 waves (2co x 4t), wave tile 64x64, 1-phase-per-K32 pipelined schedule:
// stage(s+4) -> prefetch frags(s+1) -> MFMA(s) -> vmcnt(2) -> s_barrier.
__global__ __launch_bounds__(512, 2) void selfonn_main(
    const float* __restrict__ x, const short* __restrict__ wT,
    const float* __restrict__ probs, float* __restrict__ out) {

  __shared__ __align__(16) short xs[XROWS][XPITCH];     // 71808 B
  __shared__ __align__(16) short ws[WRING][WSLOT];      // 40960 B, slot-swizzled
  __shared__ float opw[BCO][NQ];                        // 2560 B

  const int tid  = threadIdx.x;
  const int lane = tid & 63;
  const int wid  = tid >> 6;   // 0..7
  const int wm   = wid >> 2;   // co half
  const int wt   = wid & 3;    // t quarter
  const int l15  = lane & 15;
  const int lg   = lane >> 4;  // 0..3
  const int b    = blockIdx.z;
  const int co0  = blockIdx.y * BCO;
  const int t0   = blockIdx.x * BT;

  // operator softmax -> LDS
  if (tid < BCO) {
    float p[NQ];
    float mx = -1e30f;
    #pragma unroll
    for (int j = 0; j < NQ; ++j) { p[j] = probs[(co0 + tid) * NQ + j]; mx = fmaxf(mx, p[j]); }
    float s = 0.f;
    #pragma unroll
    for (int j = 0; j < NQ; ++j) { p[j] = __expf(p[j] - mx); s += p[j]; }
    float inv = 1.0f / s;
    #pragma unroll
    for (int j = 0; j < NQ; ++j) opw[tid][j] = p[j] * inv;
  }

  // ---- weight staging addresses (inverse-swizzled global source) ----
  // granule G=tid holds ws row co_l=G>>2 phys slot G&3; logical kslot=(G-(G>>3))&3
  const int soff = (tid >> 2) * KDIM + (((tid - (tid >> 3)) & 3) << 3);
  const int sdst = wid * 512;             // shorts; HW adds lane*16B
  const short* wTb = wT + (size_t)co0 * KDIM;

  // prologue: stage steps 0..3 into slots 0..3 (overlaps xs staging)
  #pragma unroll
  for (int ps = 0; ps < 4; ++ps)
    gload_lds16(wTb + ps * 32 + soff, &ws[ps][0] + sdst);

  // stage x tile once (t-transposed, bf16): xs[tl][ci] = x[b][ci][t0-4+tl]
  const float* xb = x + (size_t)b * CI * TT;
  for (int it = 0; it < 17; ++it) {
    int cell = tid + it * 512;          // 66 t-cells x 128 ci = 8448
    if (cell < XROWS / 4 * CI) {
      int ci = cell & (CI - 1);
      int tc = cell >> 7;               // 0..65
      int tg = t0 - PADL + tc * 4;
      float4v v = {0.f, 0.f, 0.f, 0.f};
      if (tg >= 0 && tg <= TT - 4)
        v = *(const float4v*)(xb + (size_t)ci * TT + tg);
      int tl = tc * 4;
      xs[tl + 0][ci] = f2bf(v[0]);
      xs[tl + 1][ci] = f2bf(v[1]);
      xs[tl + 2][ci] = f2bf(v[2]);
      xs[tl + 3][ci] = f2bf(v[3]);
    }
  }

  // ---- ds_read offset precompute (shorts) ----
  int afo[4], bfo[4];
  #pragma unroll
  for (int m = 0; m < 4; ++m) {
    int co = wm * 64 + m * 16 + l15;
    afo[m] = co * 32 + (((lg + (co >> 1)) & 3) << 3);
  }
  #pragma unroll
  for (int n = 0; n < 4; ++n)
    bfo[n] = (wt * 64 + n * 16 + l15) * XPITCH + (lg << 3);

  float4v oacc[4][4];
  float4v acc[4][4];
  #pragma unroll
  for (int m = 0; m < 4; ++m)
    #pragma unroll
    for (int n = 0; n < 4; ++n) {
      oacc[m][n] = (float4v){0.f, 0.f, 0.f, 0.f};
      acc[m][n]  = (float4v){0.f, 0.f, 0.f, 0.f};
    }

  __syncthreads();   // drains prologue stages (vmcnt 0) + xs/opw writes

  short8 frA_a[4], frA_b[4], frB_a[4], frB_b[4];
  // prefetch frags(0): slot 0, sq=0 (k=0, ci0=0)
  #pragma unroll
  for (int m = 0; m < 4; ++m) frA_a[m] = *(const short8*)(&ws[0][0] + afo[m]);
  #pragma unroll
  for (int n = 0; n < 4; ++n) frA_b[n] = *(const short8*)(&xs[0][0] + bfo[n]);

  int q = 0, sq = 0;
  int rn = 1, rs = 4, kg = 4;
  size_t woff = 4 * 32;

  #define BODY(S, CA, CB, NA, NB)                                      \
    {                                                                  \
      const int s_ = (S);                                              \
      if (s_ + 4 < NF) {                                               \
        gload_lds16(wTb + woff + soff, &ws[rs][0] + sdst);             \
        woff += 32;                                                    \
        if (++kg == NSTEP) { kg = 0; woff += (size_t)(CO - 1) * KDIM; }\
        rs = (rs == WRING - 1) ? 0 : rs + 1;                           \
      }                                                                \
      /* prefetch frags(s+1) from confirmed slot rn */                 \
      {                                                                \
        int sqn = (sq == NSTEP - 1) ? 0 : sq + 1;                      \
        int bshn = (sqn >> 2) * XPITCH + ((sqn & 3) << 5);             \
        const short* nb = &ws[rn][0];                                  \
        _Pragma("unroll") for (int m = 0; m < 4; ++m)                  \
          NA[m] = *(const short8*)(nb + afo[m]);                       \
        const short* xp = &xs[0][0] + bshn;                            \
        _Pragma("unroll") for (int n = 0; n < 4; ++n)                  \
          NB[n] = *(const short8*)(xp + bfo[n]);                       \
      }                                                                \
      __builtin_amdgcn_s_setprio(1);                                   \
      _Pragma("unroll") for (int m = 0; m < 4; ++m)                    \
        _Pragma("unroll") for (int n = 0; n < 4; ++n)                  \
          acc[m][n] = __builtin_amdgcn_mfma_f32_16x16x32_bf16(         \
              CA[m], CB[n], acc[m][n], 0, 0, 0);                       \
      __builtin_amdgcn_s_setprio(0);                                   \
      if (sq == NSTEP - 1) {                                           \
        _Pragma("unroll") for (int m = 0; m < 4; ++m) {                \
          _Pragma("unroll") for (int jj = 0; jj < 4; ++jj) {           \
            int co_l = wm * 64 + m * 16 + lg * 4 + jj;                 \
            float wqv = opw[co_l][q];                                  \
            _Pragma("unroll") for (int n = 0; n < 4; ++n) {            \
              float z = acc[m][n][jj];                                 \
              float f;                                                 \
              if (q == 0)      f = z;                                  \
              else if (q == 1) f = __sinf(z);                          \
              else if (q == 2) f = __cosf(z);                          \
              else if (q == 3) f = tanh_fast(z);                       \
              else             f = __expf(fminf(fmaxf(z, -8.f), 8.f)); \
              oacc[m][n][jj] += wqv * f;                               \
              acc[m][n][jj] = 0.f;                                     \
            }                                                          \
          }                                                            \
        }                                                              \
        ++q;                                                           \
      }                                                                \
      sq = (sq == NSTEP - 1) ? 0 : sq + 1;                             \
      rn = (rn == WRING - 1) ? 0 : rn + 1;                             \
      if (s_ + 4 < NF)       asm volatile("s_waitcnt vmcnt(2)" ::: "memory"); \
      else if (s_ + 4 == NF) asm volatile("s_waitcnt vmcnt(1)" ::: "memory"); \
      else                   asm volatile("s_waitcnt vmcnt(0)" ::: "memory"); \
      __builtin_amdgcn_s_barrier();                                    \
      asm volatile("" ::: "memory");                                   \
    }

  for (int s = 0; s < NF; s += 2) {
    BODY(s,     frA_a, frA_b, frB_a, frB_b)
    BODY(s + 1, frB_a, frB_b, frA_a, frA_b)
  }
  #undef BODY

  // store (B, CO, T) fp32
  float* ob = out + (size_t)(b * CO + co0) * TT;
  #pragma unroll
  for (int m = 0; m < 4; ++m) {
    #pragma unroll
    for (int jj = 0; jj < 4; ++jj) {
      int co_l = wm * 64 + m * 16 + lg * 4 + jj;
      int tcol = t0 + wt * 64 + l15;
      float* orow = ob + (size_t)co_l * TT + tcol;
      #pragma unroll
      for (int n = 0; n < 4; ++n)
        orow[n * 16] = oacc[m][n][jj];
    }
  }
}

extern "C" void kernel_launch(void* const* d_in, const int* in_sizes, int n_in,
                              void* d_out, int out_size, void* d_ws, size_t ws_size,
                              hipStream_t stream) {
  const float* x     = (const float*)d_in[0];
  const float* w     = (const float*)d_in[1];
  const float* probs = (const float*)d_in[2];
  float* out = (float*)d_out;
  short* wT  = (short*)d_ws;   // NQ*CO*KDIM*2 = 2.95 MB

  int nw = NQ * CO * KDIM;
  selfonn_wtrans<<<dim3((nw + 255) / 256), 256, 0, stream>>>(w, wT, nw);

  dim3 grid(TT / BT, CO / BCO, 16);
  selfonn_main<<<grid, 512, 0, stream>>>(x, wT, probs, out);
}

// Round 6
// 380.510 us; speedup vs baseline: 2.5071x; 1.4514x over previous
//
#include <hip/hip_runtime.h>

#define CI   128
#define TT   8192
#define CO   256
#define KW   9
#define NQ   5
#define PADL 4
#define KDIM (CI*KW)       // 1152
#define NSTEP 36           // K32 steps per q
#define NF (NQ*NSTEP)      // 180
#define BCO  128
#define BT   128
#define XROWS 136
#define XPITCH 136         // 272B rows: odd granule count -> octet-clean b128 reads
#define WSLOT 4096         // shorts: 128co x 32k = 8KB per ring slot, ring of 4

typedef __attribute__((ext_vector_type(8))) short short8;
typedef __attribute__((ext_vector_type(4))) float float4v;
typedef __attribute__((address_space(1))) const unsigned int ga_u32;
typedef __attribute__((address_space(3))) unsigned int la_u32;

static __device__ __forceinline__ short f2bf(float f) {
  union { float f; unsigned u; } c; c.f = f;
  unsigned u = c.u;
  return (short)((u + 0x7FFFu + ((u >> 16) & 1u)) >> 16);  // RNE
}

static __device__ __forceinline__ float tanh_fast(float z) {
  float e = __expf(2.f * z);
  return (e - 1.f) / (e + 1.f);
}

static __device__ __forceinline__ void gload_lds16(const short* g, short* l) {
  __builtin_amdgcn_global_load_lds((ga_u32*)g, (la_u32*)l, 16, 0, 0);
}

// ---- kernel 1: conv_weights (CO,CI,KW,NQ) fp32 -> wT[q][co][k*128+ci] bf16 ----
__global__ void selfonn_wtrans(const float* __restrict__ w, short* __restrict__ wT, int n) {
  int o = blockIdx.x * 256 + threadIdx.x;
  if (o >= n) return;
  int ci = o & (CI - 1);
  int k  = (o >> 7) % KW;
  int co = (o / KDIM) & (CO - 1);
  int q  = o / (KDIM * CO);
  wT[o] = f2bf(w[((co * CI + ci) * KW + k) * NQ + q]);
}

// ---- kernel 2: fused implicit-GEMM conv + nonlinearities + weighted sum ----
// 128x128 tile, 4 waves (64x64 each), 2 blocks/CU. m201-style phase:
// reads(fi) -> stage(fi+3) -> vmcnt(4) -> barrier -> MFMA(fi) -> barrier.
__global__ __launch_bounds__(256, 2) void selfonn_main(
    const float* __restrict__ x, const short* __restrict__ wT,
    const float* __restrict__ probs, float* __restrict__ out) {

  __shared__ __align__(16) short xs[XROWS][XPITCH];   // 36992 B
  __shared__ __align__(16) short ws[4][WSLOT];        // 32768 B, slot-swizzled
  __shared__ float opw[BCO][NQ];                      // 2560 B

  const int tid  = threadIdx.x;
  const int lane = tid & 63;
  const int wid  = tid >> 6;   // 0..3
  const int wm   = wid >> 1;   // co half
  const int wt   = wid & 1;    // t half
  const int l15  = lane & 15;
  const int lg   = lane >> 4;  // 0..3
  const int b    = blockIdx.z;
  const int co0  = blockIdx.y * BCO;
  const int t0   = blockIdx.x * BT;

  // operator softmax -> LDS
  if (tid < BCO) {
    float p[NQ];
    float mx = -1e30f;
    #pragma unroll
    for (int j = 0; j < NQ; ++j) { p[j] = probs[(co0 + tid) * NQ + j]; mx = fmaxf(mx, p[j]); }
    float s = 0.f;
    #pragma unroll
    for (int j = 0; j < NQ; ++j) { p[j] = __expf(p[j] - mx); s += p[j]; }
    float inv = 1.0f / s;
    #pragma unroll
    for (int j = 0; j < NQ; ++j) opw[tid][j] = p[j] * inv;
  }

  // ---- weight staging addresses (inverse-swizzled global source) ----
  // granule G holds ws row co_l=G>>2 phys slot G&3; logical kslot=(G-(G>>3))&3
  int soff0, soff1;
  {
    int G0 = tid, G1 = 256 + tid;
    soff0 = (G0 >> 2) * KDIM + (((G0 - (G0 >> 3)) & 3) << 3);
    soff1 = (G1 >> 2) * KDIM + (((G1 - (G1 >> 3)) & 3) << 3);
  }
  const int sdst0 = (wid * 64) * 8;          // shorts; HW adds lane*16B
  const int sdst1 = (256 + wid * 64) * 8;
  const short* wTb = wT + (size_t)co0 * KDIM;

  // prologue: stage steps 0,1,2 into slots 0,1,2 (overlaps xs staging)
  #pragma unroll
  for (int ps = 0; ps < 3; ++ps) {
    gload_lds16(wTb + ps * 32 + soff0, &ws[ps][0] + sdst0);
    gload_lds16(wTb + ps * 32 + soff1, &ws[ps][0] + sdst1);
  }

  // stage x tile once (t-transposed, bf16): xs[tl][ci] = x[b][ci][t0-4+tl]
  const float* xb = x + (size_t)b * CI * TT;
  #pragma unroll
  for (int it = 0; it < 17; ++it) {
    int cell = tid + it * 256;          // 0..4351
    int ci = cell & (CI - 1);
    int tc = cell >> 7;                 // 0..33
    int tg = t0 - PADL + tc * 4;
    float4v v = {0.f, 0.f, 0.f, 0.f};
    if (tg >= 0 && tg <= TT - 4)
      v = *(const float4v*)(xb + (size_t)ci * TT + tg);
    int tl = tc * 4;
    xs[tl + 0][ci] = f2bf(v[0]);
    xs[tl + 1][ci] = f2bf(v[1]);
    xs[tl + 2][ci] = f2bf(v[2]);
    xs[tl + 3][ci] = f2bf(v[3]);
  }

  // ---- ds_read offset precompute (shorts) ----
  int afo[4], bfo[4];
  #pragma unroll
  for (int m = 0; m < 4; ++m) {
    int co = wm * 64 + m * 16 + l15;
    afo[m] = co * 32 + (((lg + (co >> 1)) & 3) << 3);
  }
  #pragma unroll
  for (int n = 0; n < 4; ++n)
    bfo[n] = (wt * 64 + n * 16 + l15) * XPITCH + (lg << 3);

  float4v oacc[4][4];
  float4v acc[4][4];
  #pragma unroll
  for (int m = 0; m < 4; ++m)
    #pragma unroll
    for (int n = 0; n < 4; ++n) {
      oacc[m][n] = (float4v){0.f, 0.f, 0.f, 0.f};
      acc[m][n]  = (float4v){0.f, 0.f, 0.f, 0.f};
    }

  __syncthreads();   // drains prologue stages + xs/opw writes

  int sq = 0, q = 0;
  int s_step = 3, s_qoff = 0;   // stage cursor = fi+3

  #define BODY(SLOT, SSLOT, DOEPI, DOSTAGE, VMASM)                     \
    {                                                                  \
      /* 1. read frags(fi) */                                          \
      const short* wb = &ws[SLOT][0];                                  \
      const short* xp = &xs[0][0] + (sq >> 2) * XPITCH + ((sq & 3) << 5); \
      short8 af[4], bf[4];                                             \
      _Pragma("unroll") for (int m = 0; m < 4; ++m)                    \
        af[m] = *(const short8*)(wb + afo[m]);                         \
      _Pragma("unroll") for (int n = 0; n < 4; ++n)                    \
        bf[n] = *(const short8*)(xp + bfo[n]);                         \
      /* 2. stage(fi+3) */                                             \
      if (DOSTAGE) {                                                   \
        const short* wp = wTb + s_qoff + s_step * 32;                  \
        gload_lds16(wp + soff0, &ws[SSLOT][0] + sdst0);                \
        gload_lds16(wp + soff1, &ws[SSLOT][0] + sdst1);                \
        if (++s_step == NSTEP) { s_step = 0; s_qoff += CO * KDIM; }    \
      }                                                                \
      /* 3. counted vmem wait */                                       \
      asm volatile(VMASM ::: "memory");                                \
      /* 4. */                                                         \
      __builtin_amdgcn_s_barrier();                                    \
      /* 5. MFMA (compiler inserts lgkm waits on af/bf) */             \
      __builtin_amdgcn_s_setprio(1);                                   \
      _Pragma("unroll") for (int m = 0; m < 4; ++m)                    \
        _Pragma("unroll") for (int n = 0; n < 4; ++n)                  \
          acc[m][n] = __builtin_amdgcn_mfma_f32_16x16x32_bf16(         \
              af[m], bf[n], acc[m][n], 0, 0, 0);                       \
      __builtin_amdgcn_s_setprio(0);                                   \
      /* 6. epilogue at q-boundary */                                  \
      if (DOEPI && sq == NSTEP - 1) {                                  \
        _Pragma("unroll") for (int m = 0; m < 4; ++m) {                \
          _Pragma("unroll") for (int jj = 0; jj < 4; ++jj) {           \
            int co_l = wm * 64 + m * 16 + lg * 4 + jj;                 \
            float wqv = opw[co_l][q];                                  \
            _Pragma("unroll") for (int n = 0; n < 4; ++n) {            \
              float z = acc[m][n][jj];                                 \
              float f;                                                 \
              if (q == 0)      f = z;                                  \
              else if (q == 1) f = __sinf(z);                          \
              else if (q == 2) f = __cosf(z);                          \
              else if (q == 3) f = tanh_fast(z);                       \
              else             f = __expf(fminf(fmaxf(z, -8.f), 8.f)); \
              oacc[m][n][jj] += wqv * f;                               \
              acc[m][n][jj] = 0.f;                                     \
            }                                                          \
          }                                                            \
        }                                                              \
        ++q; sq = 0;                                                   \
      } else {                                                         \
        ++sq;                                                          \
      }                                                                \
      /* 7. */                                                         \
      __builtin_amdgcn_s_barrier();                                    \
    }

  for (int u = 0; u < 44; ++u) {        // fi = 0..175
    BODY(0, 3, 0, 1, "s_waitcnt vmcnt(4)")
    BODY(1, 0, 0, 1, "s_waitcnt vmcnt(4)")
    BODY(2, 1, 0, 1, "s_waitcnt vmcnt(4)")
    BODY(3, 2, 1, 1, "s_waitcnt vmcnt(4)")
  }
  // tail fi = 176..179
  BODY(0, 3, 0, 1, "s_waitcnt vmcnt(4)")   // stages step 179
  BODY(1, 0, 0, 0, "s_waitcnt vmcnt(2)")
  BODY(2, 1, 0, 0, "s_waitcnt vmcnt(0)")
  BODY(3, 2, 1, 0, "s_waitcnt vmcnt(0)")   // epilogue q=4
  #undef BODY

  // store (B, CO, T) fp32
  float* ob = out + (size_t)(b * CO + co0) * TT;
  #pragma unroll
  for (int m = 0; m < 4; ++m) {
    #pragma unroll
    for (int jj = 0; jj < 4; ++jj) {
      int co_l = wm * 64 + m * 16 + lg * 4 + jj;
      int tcol = t0 + wt * 64 + l15;
      float* orow = ob + (size_t)co_l * TT + tcol;
      #pragma unroll
      for (int n = 0; n < 4; ++n)
        orow[n * 16] = oacc[m][n][jj];
    }
  }
}

extern "C" void kernel_launch(void* const* d_in, const int* in_sizes, int n_in,
                              void* d_out, int out_size, void* d_ws, size_t ws_size,
                              hipStream_t stream) {
  const float* x     = (const float*)d_in[0];
  const float* w     = (const float*)d_in[1];
  const float* probs = (const float*)d_in[2];
  float* out = (float*)d_out;
  short* wT  = (short*)d_ws;   // NQ*CO*KDIM*2 = 2.95 MB

  int nw = NQ * CO * KDIM;
  selfonn_wtrans<<<dim3((nw + 255) / 256), 256, 0, stream>>>(w, wT, nw);

  dim3 grid(TT / BT, CO / BCO, 16);
  selfonn_main<<<grid, 256, 0, stream>>>(x, wT, probs, out);
}